// Round 8
// baseline (355.104 us; speedup 1.0000x reference)
//
#include <hip/hip_runtime.h>
#include <hip/hip_bf16.h>

// FourierKANLayer: N=4096, D_IN=512, D_OUT=512, G=32
// y = [cos/sin(k*LN(x)) features] @ W + bias  == GEMM M=4096,N=512,K=32768 (bf16 MFMA)
// R8: A-operand generated per-lane IN REGISTERS (R5's verified K-permuted
//     stride-4 Chebyshev gen_af) -> no A LDS, no A staging barrier cost.
//     B double-buffered LDS via global_load_lds width=16 (R7's verified path).
//     One barrier/iter, split-K=4, trig-merged 128-iter K-loop.
// ws layout: [0,16MB)  csT float2[512][4096] = (cos xn, sin xn) transposed seeds
//            [16MB]    mu_rs float2[4096] (32 KB)
//            [17MB]    bf16 weights [2][512][16384] K-PERMUTED (33.5 MB)
//            [51MB]    bf16 split-K partials [4][4096][512] (16.8 MB)

#define N_ROWS 4096
#define D_IN   512
#define D_OUT  512
#define KT     16384   // per-trig K = D_IN*G
#define BM 128
#define BN 128
#define SPLITK 4

typedef short short8 __attribute__((ext_vector_type(8)));
typedef float float4v __attribute__((ext_vector_type(4)));

__device__ inline unsigned int pack2bf(float a, float b) {
    __hip_bfloat162 h = __float22bfloat162_rn(make_float2(a, b));
    union { __hip_bfloat162 h; unsigned int u; } cv;
    cv.h = h;
    return cv.u;
}

__device__ inline unsigned short bf16_1(float a) {
    union { float f; unsigned int u; } cv;
    cv.f = a;
    unsigned int r = (cv.u + 0x7fff + ((cv.u >> 16) & 1)) >> 16;  // RN-even
    return (unsigned short)r;
}

// ---- kernel 1: per-row LayerNorm stats (mu, rsqrt(var+eps)) ----
__global__ __launch_bounds__(256) void ln_stats(const float* __restrict__ x,
        float2* __restrict__ mu_rs) {
    const int t = threadIdx.x;
    const int row = blockIdx.x * 4 + (t >> 6);
    const int lane = t & 63;
    const float4* xr = (const float4*)(x + (size_t)row * D_IN);
    float4 a = xr[lane];
    float4 c = xr[lane + 64];
    float s = a.x + a.y + a.z + a.w + c.x + c.y + c.z + c.w;
    float q = a.x * a.x + a.y * a.y + a.z * a.z + a.w * a.w
            + c.x * c.x + c.y * c.y + c.z * c.z + c.w * c.w;
    #pragma unroll
    for (int off = 32; off > 0; off >>= 1) {
        s += __shfl_down(s, off, 64);
        q += __shfl_down(q, off, 64);
    }
    if (lane == 0) {
        float mu = s * (1.f / D_IN);
        float var = q * (1.f / D_IN) - mu * mu;
        mu_rs[row] = make_float2(mu, rsqrtf(var + 1e-5f));
    }
}

// ---- kernel 2: normalize + sincos seeds, transposed coalesced write ----
__global__ __launch_bounds__(256) void feat_seed(const float* __restrict__ x,
        const float* __restrict__ w, const float* __restrict__ b,
        const float2* __restrict__ mu_rs, float2* __restrict__ csT) {
    __shared__ float2 tile[64][66];
    const int t = threadIdx.x;
    const int r0 = blockIdx.x * 64, i0 = blockIdx.y * 64;
    const int rr = t >> 6;      // 0..3
    const int cc = t & 63;
    const float wv = w[i0 + cc], bv = b[i0 + cc];
    #pragma unroll
    for (int p = 0; p < 16; ++p) {
        const int row = r0 + p * 4 + rr;
        float v = x[(size_t)row * D_IN + i0 + cc];
        float2 mr = mu_rs[row];
        float xn = (v - mr.x) * mr.y * wv + bv;
        float sn, cn;
        __sincosf(xn, &sn, &cn);
        tile[cc][p * 4 + rr] = make_float2(cn, sn);
    }
    __syncthreads();
    #pragma unroll
    for (int p = 0; p < 16; ++p) {
        const int dim = p * 4 + rr;
        csT[(size_t)(i0 + dim) * N_ROWS + r0 + cc] = tile[dim][cc];
    }
}

// ---- kernel 3: cast+PERMUTE fouriercoeffs fp32 -> bf16 (R5-verified) ----
// Wb[t][o][i][k'] holds W[t][o][i][g] at k' = (g&3)*8 + (g>>2): MFMA k-pos
// lq*8+j carries harmonic g = j*4 + lq (stride-4 runs per quad).
__global__ __launch_bounds__(256) void cvt_kernel(const float* __restrict__ fc,
        unsigned short* __restrict__ Wb) {
    const size_t r = (size_t)blockIdx.x * 256 + threadIdx.x;  // (t,o,i) row id
    const float* src = fc + r * 32;
    float v[32];
    #pragma unroll
    for (int c = 0; c < 8; ++c) {
        float4 f = ((const float4*)src)[c];
        v[c * 4 + 0] = f.x; v[c * 4 + 1] = f.y;
        v[c * 4 + 2] = f.z; v[c * 4 + 3] = f.w;
    }
    unsigned int o[16];
    #pragma unroll
    for (int p = 0; p < 16; ++p) {
        const int ka = p * 2, kb = p * 2 + 1;
        const int ga = (ka & 7) * 4 + (ka >> 3);
        const int gb = (kb & 7) * 4 + (kb >> 3);
        o[p] = pack2bf(v[ga], v[gb]);
    }
    uint4* dst = (uint4*)(Wb + r * 32);
    dst[0] = make_uint4(o[0], o[1], o[2], o[3]);
    dst[1] = make_uint4(o[4], o[5], o[6], o[7]);
    dst[2] = make_uint4(o[8], o[9], o[10], o[11]);
    dst[3] = make_uint4(o[12], o[13], o[14], o[15]);
}

// ---- per-lane A-fragment generation (R5-verified) ----
// Lane quad lq: element j = trig((j*4+lq+1)*theta) via step-4 Chebyshev.
__device__ inline short8 gen_af(float2 cs, int ttype, bool b0, bool b1) {
    const float c1 = cs.x, s1v = cs.y;
    const float c2v = c1 + c1;
    const float C2 = __builtin_fmaf(c2v, c1, -1.f);
    float cur, add1, c42;
    if (ttype == 0) {  // cos chain
        const float C3 = __builtin_fmaf(c2v, C2, -c1);
        const float C4 = __builtin_fmaf(c2v, C3, -C2);
        c42 = C4 + C4;
        cur  = b1 ? (b0 ? C4 : C3) : (b0 ? C2 : c1);
        add1 = b1 ? (b0 ? -1.f : -c1) : (b0 ? -C2 : -C3);
    } else {           // sin chain
        const float S2 = c2v * s1v;
        const float S3 = __builtin_fmaf(c2v, S2, -s1v);
        const float S4 = __builtin_fmaf(c2v, S3, -S2);
        const float C22 = C2 + C2;
        const float C4 = __builtin_fmaf(C22, C2, -1.f);
        c42 = C4 + C4;
        cur  = b1 ? (b0 ? S4 : S3) : (b0 ? S2 : s1v);
        add1 = b1 ? (b0 ? 0.f : s1v) : (b0 ? S2 : S3);
    }
    const float v0 = cur;
    const float v1 = __builtin_fmaf(c42, v0, add1);
    const float v2 = __builtin_fmaf(c42, v1, -v0);
    const float v3 = __builtin_fmaf(c42, v2, -v1);
    const float v4 = __builtin_fmaf(c42, v3, -v2);
    const float v5 = __builtin_fmaf(c42, v4, -v3);
    const float v6 = __builtin_fmaf(c42, v5, -v4);
    const float v7 = __builtin_fmaf(c42, v6, -v5);
    union { short8 s; unsigned int u[4]; } r;
    r.u[0] = pack2bf(v0, v1);
    r.u[1] = pack2bf(v2, v3);
    r.u[2] = pack2bf(v4, v5);
    r.u[3] = pack2bf(v6, v7);
    return r.s;
}

// ---- kernel 4: fused GEMM, A in regs, B dbuf LDS via gl_lds ----
// grid (32 row-tiles, 4 col-tiles, 4 k-chunks). 128 iters: 0..63 cos, 64..127 sin.
__global__ __launch_bounds__(256, 2) void fkan_gemm(const float2* __restrict__ csT,
        const unsigned short* __restrict__ Wb, unsigned short* __restrict__ pb) {
    __shared__ unsigned short Bs[2][BN * 64];   // 2 x 16 KB
    const int t = threadIdx.x;
    const int row0 = blockIdx.x * BM;
    const int col0 = blockIdx.y * BN;
    const int kz = blockIdx.z;
    const int k0 = kz * 4096;            // within-trig k offset
    const int i0 = kz * 128;             // starting input dim for this chunk
    const int l = t & 63, wv = t >> 6;
    const int wm = (wv & 1) * 64, wn = (wv >> 1) * 64;
    const int lm = l & 15, lq = l >> 4;
    const bool b0 = lq & 1, b1 = lq & 2;
    // gl_lds B staging: wave wv covers cols [col0+wv*32, +32)
    const int c8 = l & 7, s8 = l >> 3;
    const unsigned short* Bg0 = Wb + (size_t)(col0 + wv * 32 + c8) * KT + k0 + s8 * 8;
    // B-frag read base (shorts): colgrp*512 + kseg*64 + (col&7)*8
    const int bBase = ((wn >> 3) + (lm >> 3)) * 512 + lq * 64 + (lm & 7) * 8;
    // seeds: csT[dim][row]; row = row0 + wm + tm*16 + lm; dim = i0 + (iter&63)*2 + h
    const float2* csBase = csT + (size_t)i0 * N_ROWS + row0 + wm + lm;

    float4v acc[4][4];
    #pragma unroll
    for (int i = 0; i < 4; ++i)
        #pragma unroll
        for (int j = 0; j < 4; ++j)
            acc[i][j] = (float4v){0.f, 0.f, 0.f, 0.f};

    // prologue: B(0) -> Bs[0] (async), seeds(0)
    #pragma unroll
    for (int j = 0; j < 4; ++j) {
        const unsigned short* gsrc = Bg0 + (size_t)(j * 8) * KT;
        unsigned short* ldst = &Bs[0][(wv * 4 + j) * 512];
        __builtin_amdgcn_global_load_lds(
            (const __attribute__((address_space(1))) unsigned int*)gsrc,
            (__attribute__((address_space(3))) unsigned int*)ldst, 16, 0, 0);
    }
    float2 cs[8];                        // c = tm*2 + h
    #pragma unroll
    for (int c = 0; c < 8; ++c)
        cs[c] = csBase[(size_t)(c & 1) * N_ROWS + (c >> 1) * 16];
    __syncthreads();

    for (int iter = 0; iter < 128; ++iter) {
        const int p = iter & 1;
        const int ttype = iter >> 6;
        // ---- async stage B(iter+1) into Bs[p^1]
        if (iter < 127) {
            const int in = iter + 1;
            const int tt = in >> 6, ii = in & 63;
            const unsigned short* gb = Bg0 + (size_t)tt * D_OUT * KT + ii * 64;
            #pragma unroll
            for (int j = 0; j < 4; ++j) {
                const unsigned short* gsrc = gb + (size_t)(j * 8) * KT;
                unsigned short* ldst = &Bs[p ^ 1][(wv * 4 + j) * 512];
                __builtin_amdgcn_global_load_lds(
                    (const __attribute__((address_space(1))) unsigned int*)gsrc,
                    (__attribute__((address_space(3))) unsigned int*)ldst, 16, 0, 0);
            }
        }
        // ---- prefetch seeds(iter+1)
        float2 csN[8];
        if (iter < 127) {
            const int di = ((iter + 1) & 63) * 2;
            #pragma unroll
            for (int c = 0; c < 8; ++c)
                csN[c] = csBase[(size_t)(di + (c & 1)) * N_ROWS + (c >> 1) * 16];
        }
        // ---- compute: A gen'd in regs, B from Bs[p]
        #pragma unroll
        for (int h = 0; h < 2; ++h) {
            short8 af[4], bf[4];
            #pragma unroll
            for (int tm = 0; tm < 4; ++tm)
                af[tm] = gen_af(cs[tm * 2 + h], ttype, b0, b1);
            #pragma unroll
            for (int tn = 0; tn < 4; ++tn)
                bf[tn] = *(const short8*)&Bs[p][bBase + tn * 1024 + h * 256];
            #pragma unroll
            for (int tm = 0; tm < 4; ++tm)
                #pragma unroll
                for (int tn = 0; tn < 4; ++tn)
                    acc[tm][tn] = __builtin_amdgcn_mfma_f32_16x16x32_bf16(
                        af[tm], bf[tn], acc[tm][tn], 0, 0, 0);
        }
        #pragma unroll
        for (int c = 0; c < 8; ++c)
            cs[c] = csN[c];
        __syncthreads();   // publish Bs[p^1], protect Bs[p]
    }
    // epilogue: C/D layout col=lane&15, row=quad*4+reg (m89-verified)
    unsigned short* pc = pb + (size_t)kz * N_ROWS * D_OUT;
    #pragma unroll
    for (int tm = 0; tm < 4; ++tm)
        #pragma unroll
        for (int tn = 0; tn < 4; ++tn)
            #pragma unroll
            for (int r = 0; r < 4; ++r) {
                const int row = row0 + wm + tm * 16 + lq * 4 + r;
                const int col = col0 + wn + tn * 16 + lm;
                pc[(size_t)row * D_OUT + col] = bf16_1(acc[tm][tn][r]);
            }
}

// ---- kernel 5: out = bias + sum of 4 bf16 partials (coalesced) ----
__global__ __launch_bounds__(256) void reduce_kernel(const unsigned short* __restrict__ pb,
        const float* __restrict__ bias, float* __restrict__ out) {
    const size_t e = ((size_t)blockIdx.x * 256 + threadIdx.x) * 4;
    const int col = (int)(e & (D_OUT - 1));
    float4 s = *(const float4*)(bias + col);
    #pragma unroll
    for (int c = 0; c < SPLITK; ++c) {
        ushort4 u = *(const ushort4*)(pb + (size_t)c * N_ROWS * D_OUT + e);
        union { unsigned int u; float f; } f0, f1, f2, f3;
        f0.u = (unsigned int)u.x << 16;
        f1.u = (unsigned int)u.y << 16;
        f2.u = (unsigned int)u.z << 16;
        f3.u = (unsigned int)u.w << 16;
        s.x += f0.f; s.y += f1.f; s.z += f2.f; s.w += f3.f;
    }
    *(float4*)(out + e) = s;
}

extern "C" void kernel_launch(void* const* d_in, const int* in_sizes, int n_in,
                              void* d_out, int out_size, void* d_ws, size_t ws_size,
                              hipStream_t stream) {
    const float* x    = (const float*)d_in[0];
    const float* ln_w = (const float*)d_in[1];
    const float* ln_b = (const float*)d_in[2];
    const float* fc   = (const float*)d_in[3];
    const float* bias = (const float*)d_in[4];
    float* out = (float*)d_out;

    float2* csT = (float2*)d_ws;                                        // 16 MB
    float2* mu_rs = (float2*)((char*)d_ws + (16u << 20));               // 32 KB
    unsigned short* Wb = (unsigned short*)((char*)d_ws + (17u << 20));  // 33.5 MB
    unsigned short* pbp = (unsigned short*)((char*)d_ws + (51u << 20)); // 16.8 MB

    ln_stats<<<N_ROWS / 4, 256, 0, stream>>>(x, mu_rs);
    feat_seed<<<dim3(N_ROWS / 64, D_IN / 64), 256, 0, stream>>>(x, ln_w, ln_b, mu_rs, csT);
    cvt_kernel<<<2048, 256, 0, stream>>>(fc, Wb);                       // 524288 rows
    fkan_gemm<<<dim3(N_ROWS / BM, D_OUT / BN, SPLITK), 256, 0, stream>>>(csT, Wb, pbp);
    reduce_kernel<<<2048, 256, 0, stream>>>(pbp, bias, out);            // 2.10M outs
}